// Round 12
// baseline (373.099 us; speedup 1.0000x reference)
//
#include <hip/hip_runtime.h>
#include <hip/hip_bf16.h>

#define NN 100000
#define NE 1600000
#define NBUK 1563          // ceil(NN/64) 64-node dst buckets
#define NBB  196           // histogram/place blocks (8192 edges each)
#define BATCH 8192
#define CNTSZ (NBUK*NBB)   // 306348
#define SCANB 300          // ceil(CNTSZ/1024)
#define FCT 16             // fc fused row-tile

using bf16 = __hip_bfloat16;
typedef unsigned short us8_t __attribute__((ext_vector_type(8)));
static __device__ __forceinline__ float b2f(bf16 v){ return __bfloat162float(v); }
static __device__ __forceinline__ bf16 f2b(float v){ return __float2bfloat16(v); }
static __device__ __forceinline__ float us2f(unsigned u){
  unsigned x = u<<16; float f; __builtin_memcpy(&f,&x,4); return f;
}
static __device__ __forceinline__ unsigned short f2us(float v){
  bf16 b = f2b(v); unsigned short u; __builtin_memcpy(&u,&b,2); return u;
}

// canonical f32 weight-pool offsets (floats)
#define W1F   0
#define B1F   128
#define W2F   192
#define B2F   4288
#define W3F   4352
#define B3F   8448
#define FW1F  8512
#define FB1F  16704
#define FW2F  16832
#define FB2F  20928
#define WTOT  20960

// ---- dtype sniff (f32 vs bf16 storage), multi-block ----
__global__ void k_flag0(int* flag){ if(threadIdx.x==0) *flag = 0; }
__global__ void k_sniffB(const unsigned short* __restrict__ xr, int* flag){
  __shared__ int found;
  if(threadIdx.x==0) found = 0;
  __syncthreads();
  int loc = 0;
  for(int si = blockIdx.x*256 + threadIdx.x; si < 100000; si += 98*256){
    unsigned e = (xr[si*2]>>7)&0xFF;
    if(e==0xFFu || e==0u) loc = 1;
  }
  if(loc) found = 1;
  __syncthreads();
  if(threadIdx.x==0 && found) atomicOr(flag, 1);   // 1 = f32 storage
}

// convert all weights/biases into canonical f32 pool — one element/thread
__global__ void k_convert_w(const void* p0,const void* p1,const void* p2,const void* p3,
                            const void* p4,const void* p5,const void* p6,const void* p7,
                            const void* p8,const void* p9,
                            const int* __restrict__ flag, float* __restrict__ Wc){
  int t = blockIdx.x*256 + threadIdx.x;
  if(t >= WTOT) return;
  const void* ps[10] = {p0,p1,p2,p3,p4,p5,p6,p7,p8,p9};
  const int off[11] = {W1F,B1F,W2F,B2F,W3F,B3F,FW1F,FB1F,FW2F,FB2F,WTOT};
  int seg = 0;
  while(off[seg+1] <= t) seg++;
  int j = t - off[seg];
  Wc[t] = (*flag) ? ((const float*)ps[seg])[j] : b2f(((const bf16*)ps[seg])[j]);
}

// ---------------- bucket-CSR build ----------------
__global__ void k_bhist(const int* __restrict__ dst, int* __restrict__ cnt){
  __shared__ int hist[NBUK];
  for(int j=threadIdx.x; j<NBUK; j+=512) hist[j] = 0;
  __syncthreads();
  int e0 = blockIdx.x*BATCH;
  int e1 = min(NE, e0+BATCH);
  for(int e=e0+threadIdx.x; e<e1; e+=512) atomicAdd(&hist[dst[e]>>6], 1);
  __syncthreads();
  for(int j=threadIdx.x; j<NBUK; j+=512) cnt[j*NBB + blockIdx.x] = hist[j];
}
__global__ void k_scanA(const int* __restrict__ cnt, int* __restrict__ tmp,
                        int* __restrict__ bsum){
  __shared__ int sh[1024];
  int gi = blockIdx.x*1024 + threadIdx.x;
  int v = (gi < CNTSZ) ? cnt[gi] : 0;
  sh[threadIdx.x] = v; __syncthreads();
  for(int off=1; off<1024; off<<=1){
    int t = (threadIdx.x>=off) ? sh[threadIdx.x-off] : 0;
    __syncthreads();
    sh[threadIdx.x] += t;
    __syncthreads();
  }
  if(gi < CNTSZ) tmp[gi] = sh[threadIdx.x];
  if(threadIdx.x == 1023) bsum[blockIdx.x] = sh[1023];
}
__global__ void k_scanB(const int* __restrict__ bsum, int* __restrict__ boff){
  __shared__ int sh[512];
  int v = (threadIdx.x < SCANB) ? bsum[threadIdx.x] : 0;
  sh[threadIdx.x] = v; __syncthreads();
  for(int off=1; off<512; off<<=1){
    int t = (threadIdx.x>=off) ? sh[threadIdx.x-off] : 0;
    __syncthreads();
    sh[threadIdx.x] += t;
    __syncthreads();
  }
  boff[threadIdx.x] = sh[threadIdx.x] - v;   // exclusive
}
__global__ void k_scanC(int* __restrict__ cnt, const int* __restrict__ tmp,
                        const int* __restrict__ boff, int* __restrict__ bucketStart){
  int gi = blockIdx.x*1024 + threadIdx.x;
  if(gi < CNTSZ){
    int orig = cnt[gi];
    int excl = tmp[gi] - orig + boff[gi>>10];
    cnt[gi] = excl;
    if(gi % NBB == 0) bucketStart[gi/NBB] = excl;
  }
  if(gi == 0) bucketStart[NBUK] = NE;
}
__global__ void k_bplace(const int* __restrict__ src, const int* __restrict__ dst,
                         const int* __restrict__ cnt, int* __restrict__ epk){
  __shared__ int cur[NBUK];
  for(int j=threadIdx.x; j<NBUK; j+=512) cur[j] = cnt[j*NBB + blockIdx.x];
  __syncthreads();
  int e0 = blockIdx.x*BATCH, e1 = min(NE, e0+BATCH);
  for(int e=e0+threadIdx.x; e<e1; e+=512){
    int d = dst[e];
    int pos = atomicAdd(&cur[d>>6], 1);
    epk[pos] = (src[e]<<6) | (d&63);
  }
}
// in-bucket counting sort -> exact CSR (rowptr, srcS) + dinv + xd (fused)
__global__ void k_bsort(const int* __restrict__ bucketStart, const int* __restrict__ epk,
                        int* __restrict__ srcS, int* __restrict__ rowptr,
                        float* __restrict__ dinv, const void* __restrict__ xv,
                        const int* __restrict__ flag, float2* __restrict__ xd){
  __shared__ int hist[64], excl[64], cur[64];
  int tid = threadIdx.x;
  if(tid < 64) hist[tid] = 0;
  __syncthreads();
  int b = blockIdx.x, beg = bucketStart[b], end = bucketStart[b+1];
  for(int p=beg+tid; p<end; p+=256) atomicAdd(&hist[epk[p]&63], 1);
  __syncthreads();
  if(tid == 0){
    int run = 0;
    for(int j=0;j<64;j++){ excl[j] = run; run += hist[j]; }
  }
  __syncthreads();
  if(tid < 64){
    int g = b*64 + tid;
    if(g < NN){
      rowptr[g] = beg + excl[tid];
      float d = rsqrtf((float)(hist[tid] + 1));   // +1 self-loop
      dinv[g]  = d;
      float x0, x1;
      if(*flag){ float2 p = ((const float2*)xv)[g]; x0=p.x; x1=p.y; }
      else     { const bf16* xp=(const bf16*)xv; x0=b2f(xp[2*g]); x1=b2f(xp[2*g+1]); }
      xd[g] = make_float2(x0*d, x1*d);
    }
    cur[tid] = excl[tid];
  }
  if(b == 0 && tid == 0) rowptr[NN] = NE;
  __syncthreads();
  for(int p=beg+tid; p<end; p+=256){
    int pk = epk[p];
    int pos = atomicAdd(&cur[pk&63], 1);
    srcS[beg+pos] = pk>>6;
  }
}

// ---------------- layer 1 fused: propagate x (8B gathers) + 2->64 transform + relu ----------------
__global__ void k_prop1(const int* __restrict__ rowptr, const int* __restrict__ srcS,
                        const float2* __restrict__ xd, const float* __restrict__ Wc,
                        const float* __restrict__ dinv, bf16* __restrict__ h){
  __shared__ float W1s[128];
  __shared__ float bs[64];
  if(threadIdx.x < 128) W1s[threadIdx.x] = Wc[W1F + threadIdx.x];
  if(threadIdx.x < 64)  bs[threadIdx.x]  = Wc[B1F + threadIdx.x];
  __syncthreads();
  int i = blockIdx.x*256 + threadIdx.x;
  if(i >= NN) return;
  int beg = rowptr[i], end = rowptr[i+1];
  float2 self = xd[i];
  float ax0 = self.x, ay0 = self.y;
  float ax1=0,ay1=0, ax2=0,ay2=0, ax3=0,ay3=0;
  int p = beg;
  for(; p+4 <= end; p += 4){
    int s0=srcS[p], s1=srcS[p+1], s2=srcS[p+2], s3=srcS[p+3];
    float2 v0=xd[s0], v1=xd[s1], v2=xd[s2], v3=xd[s3];
    ax0+=v0.x; ay0+=v0.y; ax1+=v1.x; ay1+=v1.y;
    ax2+=v2.x; ay2+=v2.y; ax3+=v3.x; ay3+=v3.y;
  }
  for(; p<end; p++){ float2 v=xd[srcS[p]]; ax0+=v.x; ay0+=v.y; }
  float y0 = (ax0+ax1)+(ax2+ax3), y1 = (ay0+ay1)+(ay2+ay3);
  float d = dinv[i];
  unsigned short* hp = (unsigned short*)h + (size_t)i*64;
  #pragma unroll
  for(int g=0; g<8; g++){
    us8_t o;
    #pragma unroll
    for(int j=0;j<8;j++){
      int c = g*8+j;
      o[j] = f2us(fmaxf(d*(y0*W1s[c] + y1*W1s[64+c]) + bs[c], 0.0f));
    }
    *(us8_t*)(hp + g*8) = o;
  }
}

// ---------------- 64->64 transform (LDS-tiled GEMM, 4x4 tile/thread) ----------------
__global__ void __launch_bounds__(256) k_transform64(
    const bf16* __restrict__ h, const float* __restrict__ W,
    const float* __restrict__ dinv, bf16* __restrict__ s){
  __shared__ float Ws[64*64];
  __shared__ float hs[64][68];
  __shared__ float dl[64];
  int tid = threadIdx.x;
  for(int j=tid; j<4096; j+=256) Ws[j] = W[j];
  int row0 = blockIdx.x*64;
  if(tid < 64){ int r = row0+tid; dl[tid] = (r<NN)? dinv[r] : 0.0f; }
  for(int ch = tid; ch < 512; ch += 256){
    int r = ch>>3, c8 = (ch&7)*8;
    int gr = row0 + r;
    float f[8];
    if(gr < NN){
      us8_t v = *(const us8_t*)((const unsigned short*)h + (size_t)gr*64 + c8);
      #pragma unroll
      for(int j=0;j<8;j++) f[j] = us2f(v[j]);
    } else {
      #pragma unroll
      for(int j=0;j<8;j++) f[j] = 0.0f;
    }
    *(float4*)&hs[r][c8]   = make_float4(f[0],f[1],f[2],f[3]);
    *(float4*)&hs[r][c8+4] = make_float4(f[4],f[5],f[6],f[7]);
  }
  __syncthreads();
  int ty = tid>>4, tx = tid&15;
  float acc[4][4] = {{0}};
  #pragma unroll 8
  for(int k=0;k<64;k++){
    float4 b4 = *(const float4*)&Ws[k*64 + tx*4];
    float a0 = hs[ty*4+0][k];
    float a1 = hs[ty*4+1][k];
    float a2 = hs[ty*4+2][k];
    float a3 = hs[ty*4+3][k];
    acc[0][0] = fmaf(a0,b4.x,acc[0][0]); acc[0][1] = fmaf(a0,b4.y,acc[0][1]);
    acc[0][2] = fmaf(a0,b4.z,acc[0][2]); acc[0][3] = fmaf(a0,b4.w,acc[0][3]);
    acc[1][0] = fmaf(a1,b4.x,acc[1][0]); acc[1][1] = fmaf(a1,b4.y,acc[1][1]);
    acc[1][2] = fmaf(a1,b4.z,acc[1][2]); acc[1][3] = fmaf(a1,b4.w,acc[1][3]);
    acc[2][0] = fmaf(a2,b4.x,acc[2][0]); acc[2][1] = fmaf(a2,b4.y,acc[2][1]);
    acc[2][2] = fmaf(a2,b4.z,acc[2][2]); acc[2][3] = fmaf(a2,b4.w,acc[2][3]);
    acc[3][0] = fmaf(a3,b4.x,acc[3][0]); acc[3][1] = fmaf(a3,b4.y,acc[3][1]);
    acc[3][2] = fmaf(a3,b4.z,acc[3][2]); acc[3][3] = fmaf(a3,b4.w,acc[3][3]);
  }
  #pragma unroll
  for(int rr=0; rr<4; rr++){
    int r = row0 + ty*4 + rr;
    if(r < NN){
      float dv = dl[ty*4+rr];
      unsigned lo = f2us(acc[rr][0]*dv) | ((unsigned)f2us(acc[rr][1]*dv) << 16);
      unsigned hi = f2us(acc[rr][2]*dv) | ((unsigned)f2us(acc[rr][3]*dv) << 16);
      uint2 o; o.x = lo; o.y = hi;
      *(uint2*)((unsigned short*)s + (size_t)r*64 + tx*4) = o;
    }
  }
}

// ---------------- CSR aggregate + finalize: wave per node, 8 edges per wave-load ----------------
__global__ void __launch_bounds__(256) k_aggregate(
    const int* __restrict__ rowptr, const int* __restrict__ srcS,
    const bf16* __restrict__ s, const float* __restrict__ dinv,
    const float* __restrict__ bias, bf16* __restrict__ h){
  int wave = threadIdx.x>>6, lane = threadIdx.x&63;
  int i = blockIdx.x*4 + wave;            // grid = NN/4 = 25000 blocks
  if(i >= NN) return;
  int beg = rowptr[i], end = rowptr[i+1];
  int slot = lane>>3, oct = lane&7;
  const unsigned short* sp = (const unsigned short*)s;
  float a0[8] = {0,0,0,0,0,0,0,0};
  float a1[8] = {0,0,0,0,0,0,0,0};
  int p = beg;
  for(; p+16 <= end; p += 16){            // 16 edges in flight (2 per lane)
    int e0 = srcS[p + slot];
    int e1 = srcS[p + 8 + slot];
    us8_t v0 = *(const us8_t*)(sp + (size_t)e0*64 + oct*8);
    us8_t v1 = *(const us8_t*)(sp + (size_t)e1*64 + oct*8);
    #pragma unroll
    for(int j=0;j<8;j++){ a0[j] += us2f(v0[j]); a1[j] += us2f(v1[j]); }
  }
  for(; p+8 <= end; p += 8){
    int e0 = srcS[p + slot];
    us8_t v0 = *(const us8_t*)(sp + (size_t)e0*64 + oct*8);
    #pragma unroll
    for(int j=0;j<8;j++) a0[j] += us2f(v0[j]);
  }
  int rem = end - p;                      // 0..7 tail, one edge per low slot
  if(slot < rem){
    int e0 = srcS[p + slot];
    us8_t v0 = *(const us8_t*)(sp + (size_t)e0*64 + oct*8);
    #pragma unroll
    for(int j=0;j<8;j++) a1[j] += us2f(v0[j]);
  }
  float c[8];
  #pragma unroll
  for(int j=0;j<8;j++){
    float v = a0[j] + a1[j];
    v += __shfl_xor(v, 8, 64);
    v += __shfl_xor(v, 16, 64);
    v += __shfl_xor(v, 32, 64);
    c[j] = v;
  }
  us8_t sv = *(const us8_t*)(sp + (size_t)i*64 + oct*8);
  float dv = dinv[i];
  us8_t o;
  #pragma unroll
  for(int j=0;j<8;j++){
    float v = c[j] + us2f(sv[j]);
    o[j] = f2us(fmaxf(fmaf(dv, v, bias[oct*8+j]), 0.0f));
  }
  if(slot == 0)
    *(us8_t*)((unsigned short*)h + (size_t)i*64 + oct*8) = o;
}

// ---------------- fused fc1+fc2: persistent blocks, 16-row tiles, f in LDS ----------------
__global__ void __launch_bounds__(256) k_fc(const bf16* __restrict__ h,
                                            const float* __restrict__ Wc,
                                            const int* __restrict__ flag,
                                            void* __restrict__ outv){
  __shared__ float W1s[64*128];    // 32 KB
  __shared__ float W2s[128*32];    // 16 KB
  __shared__ float bs1[128];
  __shared__ float bs2[32];
  __shared__ float hs[FCT][68];    // 4.25 KB
  __shared__ float ft[FCT][132];   // 8.25 KB  -> total ~61 KB
  int tid = threadIdx.x;
  for(int j=tid; j<8192; j+=256) W1s[j] = Wc[FW1F+j];
  for(int j=tid; j<4096; j+=256) W2s[j] = Wc[FW2F+j];
  if(tid < 128) bs1[tid] = Wc[FB1F+tid];
  if(tid < 32)  bs2[tid] = Wc[FB2F+tid];
  int fl = *flag;
  int tr = tid>>4, tc = tid&15;    // 16 rows x 16 col-groups
  for(int t = blockIdx.x; t < (NN+FCT-1)/FCT; t += 1024){
    int row0 = t*FCT;
    __syncthreads();               // prev iter's ft reads done
    if(tid < 128){                 // stage 16x64 h tile (us8 chunks)
      int r = tid>>3, c8 = (tid&7)*8, gr = row0 + r;
      float fv[8];
      if(gr < NN){
        us8_t v = *(const us8_t*)((const unsigned short*)h + (size_t)gr*64 + c8);
        #pragma unroll
        for(int j=0;j<8;j++) fv[j] = us2f(v[j]);
      } else {
        #pragma unroll
        for(int j=0;j<8;j++) fv[j] = 0.0f;
      }
      *(float4*)&hs[r][c8]   = make_float4(fv[0],fv[1],fv[2],fv[3]);
      *(float4*)&hs[r][c8+4] = make_float4(fv[4],fv[5],fv[6],fv[7]);
    }
    __syncthreads();
    // fc1: row tr, cols tc*8..+7
    float acc[8] = {0,0,0,0,0,0,0,0};
    #pragma unroll 4
    for(int k=0;k<64;k++){
      float a = hs[tr][k];
      float4 b0 = *(const float4*)&W1s[k*128 + tc*8];
      float4 b1 = *(const float4*)&W1s[k*128 + tc*8 + 4];
      acc[0]=fmaf(a,b0.x,acc[0]); acc[1]=fmaf(a,b0.y,acc[1]);
      acc[2]=fmaf(a,b0.z,acc[2]); acc[3]=fmaf(a,b0.w,acc[3]);
      acc[4]=fmaf(a,b1.x,acc[4]); acc[5]=fmaf(a,b1.y,acc[5]);
      acc[6]=fmaf(a,b1.z,acc[6]); acc[7]=fmaf(a,b1.w,acc[7]);
    }
    #pragma unroll
    for(int j=0;j<8;j++) ft[tr][tc*8+j] = fmaxf(acc[j] + bs1[tc*8+j], 0.0f);
    __syncthreads();
    // fc2: row tr, cols tc*2..+1
    float o0 = 0.0f, o1 = 0.0f;
    #pragma unroll 8
    for(int k=0;k<128;k++){
      float a = ft[tr][k];
      o0 = fmaf(a, W2s[k*32 + tc*2],     o0);
      o1 = fmaf(a, W2s[k*32 + tc*2 + 1], o1);
    }
    int gr = row0 + tr;
    if(gr < NN){
      o0 += bs2[tc*2]; o1 += bs2[tc*2+1];
      if(fl){
        *(float2*)((float*)outv + (size_t)gr*32 + tc*2) = make_float2(o0, o1);
      } else {
        unsigned w = f2us(o0) | ((unsigned)f2us(o1) << 16);
        *(unsigned*)((unsigned short*)outv + (size_t)gr*32 + tc*2) = w;
      }
    }
  }
}

extern "C" void kernel_launch(void* const* d_in, const int* in_sizes, int n_in,
                              void* d_out, int out_size, void* d_ws, size_t ws_size,
                              hipStream_t stream){
  const void* x   = d_in[0];
  const int*  ei  = (const int*)d_in[1];
  const int* srcI = ei;        // edge_index[0]
  const int* dstI = ei + NE;   // edge_index[1]

  // workspace layout (bytes); total ~42.5 MB
  char*   base   = (char*)d_ws;
  int*    flag   = (int*)   (base + 0);          // 256
  float*  Wc     = (float*) (base + 256);        // 83840 -> 84096
  int*    bstart = (int*)   (base + 84224);      // 6256
  int*    cnt    = (int*)   (base + 90624);      // 1225392
  int*    tmpS   = (int*)   (base + 1316096);    // 1225392
  int*    bsum   = (int*)   (base + 2541568);    // 2048
  int*    boff   = (int*)   (base + 2543616);    // 2048
  float*  dinv   = (float*) (base + 2545664);    // 400000
  int*    rowptr = (int*)   (base + 2945664);    // 400004
  int*    epk    = (int*)   (base + 3345792);    // 6400000
  int*    srcS   = (int*)   (base + 9745792);    // 6400000
  float2* xd     = (float2*)(base + 16145792);   // 800000
  bf16*   s      = (bf16*)  (base + 16945792);   // 12800000
  bf16*   h      = (bf16*)  (base + 29745792);   // 12800000 -> ends 42545792

  // dtype sniff + weight conversion
  k_flag0    <<<1, 64, 0, stream>>>(flag);
  k_sniffB   <<<98, 256, 0, stream>>>((const unsigned short*)x, flag);
  k_convert_w<<<(WTOT+255)/256, 256, 0, stream>>>(
      d_in[2], d_in[3], d_in[4], d_in[5], d_in[6],
      d_in[7], d_in[8], d_in[9], d_in[10], d_in[11], flag, Wc);

  // bucket-grouped build: hist -> parallel scan -> place -> in-bucket sort (+xd)
  k_bhist <<<NBB, 512, 0, stream>>>(dstI, cnt);
  k_scanA <<<SCANB, 1024, 0, stream>>>(cnt, tmpS, bsum);
  k_scanB <<<1, 512, 0, stream>>>(bsum, boff);
  k_scanC <<<SCANB, 1024, 0, stream>>>(cnt, tmpS, boff, bstart);
  k_bplace<<<NBB, 512, 0, stream>>>(srcI, dstI, cnt, epk);
  k_bsort <<<NBUK, 256, 0, stream>>>(bstart, epk, srcS, rowptr, dinv, x, flag, xd);

  // layer 1 (2 -> 64): fused propagate + transform + relu
  k_prop1<<<(NN+255)/256, 256, 0, stream>>>(rowptr, srcS, xd, Wc, dinv, h);

  // layer 2 (64 -> 64)
  k_transform64<<<(NN+63)/64, 256, 0, stream>>>(h, Wc+W2F, dinv, s);
  k_aggregate  <<<NN/4, 256, 0, stream>>>(rowptr, srcS, s, dinv, Wc+B2F, h);

  // layer 3 (64 -> 64)
  k_transform64<<<(NN+63)/64, 256, 0, stream>>>(h, Wc+W3F, dinv, s);
  k_aggregate  <<<NN/4, 256, 0, stream>>>(rowptr, srcS, s, dinv, Wc+B3F, h);

  // fused fc1+fc2 (f lives in LDS)
  k_fc<<<1024, 256, 0, stream>>>(h, Wc, flag, d_out);
}

// Round 13
// 329.059 us; speedup vs baseline: 1.1338x; 1.1338x over previous
//
#include <hip/hip_runtime.h>
#include <hip/hip_bf16.h>

#define NN 100000
#define NE 1600000
#define NBUK 1563          // ceil(NN/64) 64-node dst buckets
#define NBB  196           // histogram/place blocks (8192 edges each)
#define BATCH 8192
#define CNTSZ (NBUK*NBB)   // 306348
#define SCANB 300          // ceil(CNTSZ/1024)

using bf16 = __hip_bfloat16;
typedef unsigned short us8_t __attribute__((ext_vector_type(8)));
static __device__ __forceinline__ float b2f(bf16 v){ return __bfloat162float(v); }
static __device__ __forceinline__ bf16 f2b(float v){ return __float2bfloat16(v); }
static __device__ __forceinline__ float us2f(unsigned u){
  unsigned x = u<<16; float f; __builtin_memcpy(&f,&x,4); return f;
}
static __device__ __forceinline__ unsigned short f2us(float v){
  bf16 b = f2b(v); unsigned short u; __builtin_memcpy(&u,&b,2); return u;
}

// canonical f32 weight-pool offsets (floats)
#define W1F   0
#define B1F   128
#define W2F   192
#define B2F   4288
#define W3F   4352
#define B3F   8448
#define FW1F  8512
#define FB1F  16704
#define FW2F  16832
#define FB2F  20928
#define WTOT  20960

// ---- dtype sniff (f32 vs bf16 storage), multi-block ----
__global__ void k_flag0(int* flag){ if(threadIdx.x==0) *flag = 0; }
__global__ void k_sniffB(const unsigned short* __restrict__ xr, int* flag){
  __shared__ int found;
  if(threadIdx.x==0) found = 0;
  __syncthreads();
  int loc = 0;
  for(int si = blockIdx.x*256 + threadIdx.x; si < 100000; si += 98*256){
    unsigned e = (xr[si*2]>>7)&0xFF;
    if(e==0xFFu || e==0u) loc = 1;
  }
  if(loc) found = 1;
  __syncthreads();
  if(threadIdx.x==0 && found) atomicOr(flag, 1);   // 1 = f32 storage
}

// convert all weights/biases into canonical f32 pool — one element/thread
__global__ void k_convert_w(const void* p0,const void* p1,const void* p2,const void* p3,
                            const void* p4,const void* p5,const void* p6,const void* p7,
                            const void* p8,const void* p9,
                            const int* __restrict__ flag, float* __restrict__ Wc){
  int t = blockIdx.x*256 + threadIdx.x;
  if(t >= WTOT) return;
  const void* ps[10] = {p0,p1,p2,p3,p4,p5,p6,p7,p8,p9};
  const int off[11] = {W1F,B1F,W2F,B2F,W3F,B3F,FW1F,FB1F,FW2F,FB2F,WTOT};
  int seg = 0;
  while(off[seg+1] <= t) seg++;
  int j = t - off[seg];
  Wc[t] = (*flag) ? ((const float*)ps[seg])[j] : b2f(((const bf16*)ps[seg])[j]);
}

// ---------------- bucket-CSR build ----------------
__global__ void k_bhist(const int* __restrict__ dst, int* __restrict__ cnt){
  __shared__ int hist[NBUK];
  for(int j=threadIdx.x; j<NBUK; j+=512) hist[j] = 0;
  __syncthreads();
  int e0 = blockIdx.x*BATCH;
  int e1 = min(NE, e0+BATCH);
  for(int e=e0+threadIdx.x; e<e1; e+=512) atomicAdd(&hist[dst[e]>>6], 1);
  __syncthreads();
  for(int j=threadIdx.x; j<NBUK; j+=512) cnt[j*NBB + blockIdx.x] = hist[j];
}
__global__ void k_scanA(const int* __restrict__ cnt, int* __restrict__ tmp,
                        int* __restrict__ bsum){
  __shared__ int sh[1024];
  int gi = blockIdx.x*1024 + threadIdx.x;
  int v = (gi < CNTSZ) ? cnt[gi] : 0;
  sh[threadIdx.x] = v; __syncthreads();
  for(int off=1; off<1024; off<<=1){
    int t = (threadIdx.x>=off) ? sh[threadIdx.x-off] : 0;
    __syncthreads();
    sh[threadIdx.x] += t;
    __syncthreads();
  }
  if(gi < CNTSZ) tmp[gi] = sh[threadIdx.x];
  if(threadIdx.x == 1023) bsum[blockIdx.x] = sh[1023];
}
__global__ void k_scanB(const int* __restrict__ bsum, int* __restrict__ boff){
  __shared__ int sh[512];
  int v = (threadIdx.x < SCANB) ? bsum[threadIdx.x] : 0;
  sh[threadIdx.x] = v; __syncthreads();
  for(int off=1; off<512; off<<=1){
    int t = (threadIdx.x>=off) ? sh[threadIdx.x-off] : 0;
    __syncthreads();
    sh[threadIdx.x] += t;
    __syncthreads();
  }
  boff[threadIdx.x] = sh[threadIdx.x] - v;   // exclusive
}
__global__ void k_scanC(int* __restrict__ cnt, const int* __restrict__ tmp,
                        const int* __restrict__ boff, int* __restrict__ bucketStart){
  int gi = blockIdx.x*1024 + threadIdx.x;
  if(gi < CNTSZ){
    int orig = cnt[gi];
    int excl = tmp[gi] - orig + boff[gi>>10];
    cnt[gi] = excl;
    if(gi % NBB == 0) bucketStart[gi/NBB] = excl;
  }
  if(gi == 0) bucketStart[NBUK] = NE;
}
__global__ void k_bplace(const int* __restrict__ src, const int* __restrict__ dst,
                         const int* __restrict__ cnt, int* __restrict__ epk){
  __shared__ int cur[NBUK];
  for(int j=threadIdx.x; j<NBUK; j+=512) cur[j] = cnt[j*NBB + blockIdx.x];
  __syncthreads();
  int e0 = blockIdx.x*BATCH, e1 = min(NE, e0+BATCH);
  for(int e=e0+threadIdx.x; e<e1; e+=512){
    int d = dst[e];
    int pos = atomicAdd(&cur[d>>6], 1);
    epk[pos] = (src[e]<<6) | (d&63);
  }
}
// in-bucket counting sort -> exact CSR (rowptr, srcS) + dinv + xd (fused)
__global__ void k_bsort(const int* __restrict__ bucketStart, const int* __restrict__ epk,
                        int* __restrict__ srcS, int* __restrict__ rowptr,
                        float* __restrict__ dinv, const void* __restrict__ xv,
                        const int* __restrict__ flag, float2* __restrict__ xd){
  __shared__ int hist[64], excl[64], cur[64];
  int tid = threadIdx.x;
  if(tid < 64) hist[tid] = 0;
  __syncthreads();
  int b = blockIdx.x, beg = bucketStart[b], end = bucketStart[b+1];
  for(int p=beg+tid; p<end; p+=256) atomicAdd(&hist[epk[p]&63], 1);
  __syncthreads();
  if(tid == 0){
    int run = 0;
    for(int j=0;j<64;j++){ excl[j] = run; run += hist[j]; }
  }
  __syncthreads();
  if(tid < 64){
    int g = b*64 + tid;
    if(g < NN){
      rowptr[g] = beg + excl[tid];
      float d = rsqrtf((float)(hist[tid] + 1));   // +1 self-loop
      dinv[g]  = d;
      float x0, x1;
      if(*flag){ float2 p = ((const float2*)xv)[g]; x0=p.x; x1=p.y; }
      else     { const bf16* xp=(const bf16*)xv; x0=b2f(xp[2*g]); x1=b2f(xp[2*g+1]); }
      xd[g] = make_float2(x0*d, x1*d);
    }
    cur[tid] = excl[tid];
  }
  if(b == 0 && tid == 0) rowptr[NN] = NE;
  __syncthreads();
  for(int p=beg+tid; p<end; p+=256){
    int pk = epk[p];
    int pos = atomicAdd(&cur[pk&63], 1);
    srcS[beg+pos] = pk>>6;
  }
}

// ---------------- layer 1 fused: propagate x (8B gathers) + 2->64 transform + relu ----------------
__global__ void k_prop1(const int* __restrict__ rowptr, const int* __restrict__ srcS,
                        const float2* __restrict__ xd, const float* __restrict__ Wc,
                        const float* __restrict__ dinv, bf16* __restrict__ h){
  __shared__ float W1s[128];
  __shared__ float bs[64];
  if(threadIdx.x < 128) W1s[threadIdx.x] = Wc[W1F + threadIdx.x];
  if(threadIdx.x < 64)  bs[threadIdx.x]  = Wc[B1F + threadIdx.x];
  __syncthreads();
  int i = blockIdx.x*256 + threadIdx.x;
  if(i >= NN) return;
  int beg = rowptr[i], end = rowptr[i+1];
  float2 self = xd[i];
  float ax0 = self.x, ay0 = self.y;
  float ax1=0,ay1=0, ax2=0,ay2=0, ax3=0,ay3=0;
  int p = beg;
  for(; p+4 <= end; p += 4){
    int s0=srcS[p], s1=srcS[p+1], s2=srcS[p+2], s3=srcS[p+3];
    float2 v0=xd[s0], v1=xd[s1], v2=xd[s2], v3=xd[s3];
    ax0+=v0.x; ay0+=v0.y; ax1+=v1.x; ay1+=v1.y;
    ax2+=v2.x; ay2+=v2.y; ax3+=v3.x; ay3+=v3.y;
  }
  for(; p<end; p++){ float2 v=xd[srcS[p]]; ax0+=v.x; ay0+=v.y; }
  float y0 = (ax0+ax1)+(ax2+ax3), y1 = (ay0+ay1)+(ay2+ay3);
  float d = dinv[i];
  unsigned short* hp = (unsigned short*)h + (size_t)i*64;
  #pragma unroll
  for(int g=0; g<8; g++){
    us8_t o;
    #pragma unroll
    for(int j=0;j<8;j++){
      int c = g*8+j;
      o[j] = f2us(fmaxf(d*(y0*W1s[c] + y1*W1s[64+c]) + bs[c], 0.0f));
    }
    *(us8_t*)(hp + g*8) = o;
  }
}

// ---------------- 64->64 transform (LDS-tiled GEMM, 4x4 tile/thread) ----------------
__global__ void __launch_bounds__(256) k_transform64(
    const bf16* __restrict__ h, const float* __restrict__ W,
    const float* __restrict__ dinv, bf16* __restrict__ s){
  __shared__ float Ws[64*64];
  __shared__ float hs[64][68];
  __shared__ float dl[64];
  int tid = threadIdx.x;
  for(int j=tid; j<4096; j+=256) Ws[j] = W[j];
  int row0 = blockIdx.x*64;
  if(tid < 64){ int r = row0+tid; dl[tid] = (r<NN)? dinv[r] : 0.0f; }
  for(int ch = tid; ch < 512; ch += 256){
    int r = ch>>3, c8 = (ch&7)*8;
    int gr = row0 + r;
    float f[8];
    if(gr < NN){
      us8_t v = *(const us8_t*)((const unsigned short*)h + (size_t)gr*64 + c8);
      #pragma unroll
      for(int j=0;j<8;j++) f[j] = us2f(v[j]);
    } else {
      #pragma unroll
      for(int j=0;j<8;j++) f[j] = 0.0f;
    }
    *(float4*)&hs[r][c8]   = make_float4(f[0],f[1],f[2],f[3]);
    *(float4*)&hs[r][c8+4] = make_float4(f[4],f[5],f[6],f[7]);
  }
  __syncthreads();
  int ty = tid>>4, tx = tid&15;
  float acc[4][4] = {{0}};
  #pragma unroll 8
  for(int k=0;k<64;k++){
    float4 b4 = *(const float4*)&Ws[k*64 + tx*4];
    float a0 = hs[ty*4+0][k];
    float a1 = hs[ty*4+1][k];
    float a2 = hs[ty*4+2][k];
    float a3 = hs[ty*4+3][k];
    acc[0][0] = fmaf(a0,b4.x,acc[0][0]); acc[0][1] = fmaf(a0,b4.y,acc[0][1]);
    acc[0][2] = fmaf(a0,b4.z,acc[0][2]); acc[0][3] = fmaf(a0,b4.w,acc[0][3]);
    acc[1][0] = fmaf(a1,b4.x,acc[1][0]); acc[1][1] = fmaf(a1,b4.y,acc[1][1]);
    acc[1][2] = fmaf(a1,b4.z,acc[1][2]); acc[1][3] = fmaf(a1,b4.w,acc[1][3]);
    acc[2][0] = fmaf(a2,b4.x,acc[2][0]); acc[2][1] = fmaf(a2,b4.y,acc[2][1]);
    acc[2][2] = fmaf(a2,b4.z,acc[2][2]); acc[2][3] = fmaf(a2,b4.w,acc[2][3]);
    acc[3][0] = fmaf(a3,b4.x,acc[3][0]); acc[3][1] = fmaf(a3,b4.y,acc[3][1]);
    acc[3][2] = fmaf(a3,b4.z,acc[3][2]); acc[3][3] = fmaf(a3,b4.w,acc[3][3]);
  }
  #pragma unroll
  for(int rr=0; rr<4; rr++){
    int r = row0 + ty*4 + rr;
    if(r < NN){
      float dv = dl[ty*4+rr];
      unsigned lo = f2us(acc[rr][0]*dv) | ((unsigned)f2us(acc[rr][1]*dv) << 16);
      unsigned hi = f2us(acc[rr][2]*dv) | ((unsigned)f2us(acc[rr][3]*dv) << 16);
      uint2 o; o.x = lo; o.y = hi;
      *(uint2*)((unsigned short*)s + (size_t)r*64 + tx*4) = o;
    }
  }
}

// ---------------- CSR aggregate + finalize: wave per node, 8 edges per wave-load ----------------
__global__ void __launch_bounds__(256) k_aggregate(
    const int* __restrict__ rowptr, const int* __restrict__ srcS,
    const bf16* __restrict__ s, const float* __restrict__ dinv,
    const float* __restrict__ bias, bf16* __restrict__ h){
  int wave = threadIdx.x>>6, lane = threadIdx.x&63;
  int i = blockIdx.x*4 + wave;            // grid = NN/4 = 25000 blocks
  if(i >= NN) return;
  int beg = rowptr[i], end = rowptr[i+1];
  int slot = lane>>3, oct = lane&7;
  const unsigned short* sp = (const unsigned short*)s;
  float a0[8] = {0,0,0,0,0,0,0,0};
  float a1[8] = {0,0,0,0,0,0,0,0};
  int p = beg;
  for(; p+16 <= end; p += 16){            // 16 edges in flight (2 per lane)
    int e0 = srcS[p + slot];
    int e1 = srcS[p + 8 + slot];
    us8_t v0 = *(const us8_t*)(sp + (size_t)e0*64 + oct*8);
    us8_t v1 = *(const us8_t*)(sp + (size_t)e1*64 + oct*8);
    #pragma unroll
    for(int j=0;j<8;j++){ a0[j] += us2f(v0[j]); a1[j] += us2f(v1[j]); }
  }
  for(; p+8 <= end; p += 8){
    int e0 = srcS[p + slot];
    us8_t v0 = *(const us8_t*)(sp + (size_t)e0*64 + oct*8);
    #pragma unroll
    for(int j=0;j<8;j++) a0[j] += us2f(v0[j]);
  }
  int rem = end - p;                      // 0..7 tail, one edge per low slot
  if(slot < rem){
    int e0 = srcS[p + slot];
    us8_t v0 = *(const us8_t*)(sp + (size_t)e0*64 + oct*8);
    #pragma unroll
    for(int j=0;j<8;j++) a1[j] += us2f(v0[j]);
  }
  float c[8];
  #pragma unroll
  for(int j=0;j<8;j++){
    float v = a0[j] + a1[j];
    v += __shfl_xor(v, 8, 64);
    v += __shfl_xor(v, 16, 64);
    v += __shfl_xor(v, 32, 64);
    c[j] = v;
  }
  us8_t sv = *(const us8_t*)(sp + (size_t)i*64 + oct*8);
  float dv = dinv[i];
  us8_t o;
  #pragma unroll
  for(int j=0;j<8;j++){
    float v = c[j] + us2f(sv[j]);
    o[j] = f2us(fmaxf(fmaf(dv, v, bias[oct*8+j]), 0.0f));
  }
  if(slot == 0)
    *(us8_t*)((unsigned short*)h + (size_t)i*64 + oct*8) = o;
}

// ---------------- fc1: [NN x 64] @ [64 x 128] + b, relu -> f (bf16) ----------------
__global__ void __launch_bounds__(256) k_fc1(const bf16* __restrict__ h,
                                             const float* __restrict__ Wc,
                                             bf16* __restrict__ f){
  __shared__ float W1s[64*128];
  __shared__ float hs[64][68];
  __shared__ float bs[128];
  int tid = threadIdx.x;
  for(int j=tid; j<8192; j+=256) W1s[j] = Wc[FW1F+j];
  if(tid < 128) bs[tid] = Wc[FB1F+tid];
  int row0 = blockIdx.x*64;
  for(int ch = tid; ch < 512; ch += 256){
    int r = ch>>3, c8 = (ch&7)*8, gr = row0 + r;
    float fv[8];
    if(gr < NN){
      us8_t v = *(const us8_t*)((const unsigned short*)h + (size_t)gr*64 + c8);
      #pragma unroll
      for(int j=0;j<8;j++) fv[j] = us2f(v[j]);
    } else {
      #pragma unroll
      for(int j=0;j<8;j++) fv[j] = 0.0f;
    }
    *(float4*)&hs[r][c8]   = make_float4(fv[0],fv[1],fv[2],fv[3]);
    *(float4*)&hs[r][c8+4] = make_float4(fv[4],fv[5],fv[6],fv[7]);
  }
  __syncthreads();
  int ty = tid>>4, tx = tid&15;
  float acc[4][8] = {{0}};
  #pragma unroll 4
  for(int k=0;k<64;k++){
    float4 b0 = *(const float4*)&W1s[k*128 + tx*8];
    float4 b1 = *(const float4*)&W1s[k*128 + tx*8 + 4];
    float a0 = hs[ty*4+0][k], a1 = hs[ty*4+1][k];
    float a2 = hs[ty*4+2][k], a3 = hs[ty*4+3][k];
    acc[0][0]=fmaf(a0,b0.x,acc[0][0]); acc[0][1]=fmaf(a0,b0.y,acc[0][1]);
    acc[0][2]=fmaf(a0,b0.z,acc[0][2]); acc[0][3]=fmaf(a0,b0.w,acc[0][3]);
    acc[0][4]=fmaf(a0,b1.x,acc[0][4]); acc[0][5]=fmaf(a0,b1.y,acc[0][5]);
    acc[0][6]=fmaf(a0,b1.z,acc[0][6]); acc[0][7]=fmaf(a0,b1.w,acc[0][7]);
    acc[1][0]=fmaf(a1,b0.x,acc[1][0]); acc[1][1]=fmaf(a1,b0.y,acc[1][1]);
    acc[1][2]=fmaf(a1,b0.z,acc[1][2]); acc[1][3]=fmaf(a1,b0.w,acc[1][3]);
    acc[1][4]=fmaf(a1,b1.x,acc[1][4]); acc[1][5]=fmaf(a1,b1.y,acc[1][5]);
    acc[1][6]=fmaf(a1,b1.z,acc[1][6]); acc[1][7]=fmaf(a1,b1.w,acc[1][7]);
    acc[2][0]=fmaf(a2,b0.x,acc[2][0]); acc[2][1]=fmaf(a2,b0.y,acc[2][1]);
    acc[2][2]=fmaf(a2,b0.z,acc[2][2]); acc[2][3]=fmaf(a2,b0.w,acc[2][3]);
    acc[2][4]=fmaf(a2,b1.x,acc[2][4]); acc[2][5]=fmaf(a2,b1.y,acc[2][5]);
    acc[2][6]=fmaf(a2,b1.z,acc[2][6]); acc[2][7]=fmaf(a2,b1.w,acc[2][7]);
    acc[3][0]=fmaf(a3,b0.x,acc[3][0]); acc[3][1]=fmaf(a3,b0.y,acc[3][1]);
    acc[3][2]=fmaf(a3,b0.z,acc[3][2]); acc[3][3]=fmaf(a3,b0.w,acc[3][3]);
    acc[3][4]=fmaf(a3,b1.x,acc[3][4]); acc[3][5]=fmaf(a3,b1.y,acc[3][5]);
    acc[3][6]=fmaf(a3,b1.z,acc[3][6]); acc[3][7]=fmaf(a3,b1.w,acc[3][7]);
  }
  #pragma unroll
  for(int r=0;r<4;r++){
    int gr = row0 + ty*4 + r;
    if(gr < NN){
      us8_t o;
      #pragma unroll
      for(int j=0;j<8;j++) o[j] = f2us(fmaxf(acc[r][j] + bs[tx*8+j], 0.0f));
      *(us8_t*)((unsigned short*)f + (size_t)gr*128 + tx*8) = o;
    }
  }
}

// ---------------- fc2: [NN x 128] @ [128 x 32] + b -> out ----------------
__global__ void __launch_bounds__(256) k_fc2(const bf16* __restrict__ f,
                                             const float* __restrict__ Wc,
                                             const int* __restrict__ flag,
                                             void* __restrict__ outv){
  __shared__ float W2s[128*32];
  __shared__ float fs[64][132];
  __shared__ float bs[32];
  int tid = threadIdx.x;
  for(int j=tid; j<4096; j+=256) W2s[j] = Wc[FW2F+j];
  if(tid < 32) bs[tid] = Wc[FB2F+tid];
  int row0 = blockIdx.x*64;
  for(int ch = tid; ch < 1024; ch += 256){
    int r = ch>>4, c8 = (ch&15)*8, gr = row0 + r;
    float fv[8];
    if(gr < NN){
      us8_t v = *(const us8_t*)((const unsigned short*)f + (size_t)gr*128 + c8);
      #pragma unroll
      for(int j=0;j<8;j++) fv[j] = us2f(v[j]);
    } else {
      #pragma unroll
      for(int j=0;j<8;j++) fv[j] = 0.0f;
    }
    *(float4*)&fs[r][c8]   = make_float4(fv[0],fv[1],fv[2],fv[3]);
    *(float4*)&fs[r][c8+4] = make_float4(fv[4],fv[5],fv[6],fv[7]);
  }
  __syncthreads();
  int ty = tid>>3, tx = tid&7;
  float acc[2][4] = {{0}};
  #pragma unroll 8
  for(int k=0;k<128;k++){
    float4 b4 = *(const float4*)&W2s[k*32 + tx*4];
    float a0 = fs[ty*2+0][k], a1 = fs[ty*2+1][k];
    acc[0][0]=fmaf(a0,b4.x,acc[0][0]); acc[0][1]=fmaf(a0,b4.y,acc[0][1]);
    acc[0][2]=fmaf(a0,b4.z,acc[0][2]); acc[0][3]=fmaf(a0,b4.w,acc[0][3]);
    acc[1][0]=fmaf(a1,b4.x,acc[1][0]); acc[1][1]=fmaf(a1,b4.y,acc[1][1]);
    acc[1][2]=fmaf(a1,b4.z,acc[1][2]); acc[1][3]=fmaf(a1,b4.w,acc[1][3]);
  }
  int fl = *flag;
  #pragma unroll
  for(int r=0;r<2;r++){
    int gr = row0 + ty*2 + r;
    if(gr < NN){
      float o0 = acc[r][0]+bs[tx*4+0], o1 = acc[r][1]+bs[tx*4+1];
      float o2 = acc[r][2]+bs[tx*4+2], o3 = acc[r][3]+bs[tx*4+3];
      if(fl){
        *(float4*)((float*)outv + (size_t)gr*32 + tx*4) = make_float4(o0,o1,o2,o3);
      } else {
        unsigned lo = f2us(o0) | ((unsigned)f2us(o1)<<16);
        unsigned hi = f2us(o2) | ((unsigned)f2us(o3)<<16);
        uint2 o; o.x = lo; o.y = hi;
        *(uint2*)((unsigned short*)outv + (size_t)gr*32 + tx*4) = o;
      }
    }
  }
}

extern "C" void kernel_launch(void* const* d_in, const int* in_sizes, int n_in,
                              void* d_out, int out_size, void* d_ws, size_t ws_size,
                              hipStream_t stream){
  const void* x   = d_in[0];
  const int*  ei  = (const int*)d_in[1];
  const int* srcI = ei;        // edge_index[0]
  const int* dstI = ei + NE;   // edge_index[1]

  // workspace layout (bytes); total ~68 MB
  char*   base   = (char*)d_ws;
  int*    flag   = (int*)   (base + 0);          // 256
  float*  Wc     = (float*) (base + 256);        // 83840 -> 84096
  int*    bstart = (int*)   (base + 84224);      // 6256
  int*    cnt    = (int*)   (base + 90624);      // 1225392
  int*    tmpS   = (int*)   (base + 1316096);    // 1225392
  int*    bsum   = (int*)   (base + 2541568);    // 2048
  int*    boff   = (int*)   (base + 2543616);    // 2048
  float*  dinv   = (float*) (base + 2545664);    // 400000
  int*    rowptr = (int*)   (base + 2945664);    // 400004
  int*    epk    = (int*)   (base + 3345792);    // 6400000
  int*    srcS   = (int*)   (base + 9745792);    // 6400000
  float2* xd     = (float2*)(base + 16145792);   // 800000
  bf16*   s      = (bf16*)  (base + 16945792);   // 12800000
  bf16*   h      = (bf16*)  (base + 29745792);   // 12800000
  bf16*   f      = (bf16*)  (base + 42545792);   // 25600000 -> ends 68145792

  // dtype sniff + weight conversion
  k_flag0    <<<1, 64, 0, stream>>>(flag);
  k_sniffB   <<<98, 256, 0, stream>>>((const unsigned short*)x, flag);
  k_convert_w<<<(WTOT+255)/256, 256, 0, stream>>>(
      d_in[2], d_in[3], d_in[4], d_in[5], d_in[6],
      d_in[7], d_in[8], d_in[9], d_in[10], d_in[11], flag, Wc);

  // bucket-grouped build: hist -> parallel scan -> place -> in-bucket sort (+xd)
  k_bhist <<<NBB, 512, 0, stream>>>(dstI, cnt);
  k_scanA <<<SCANB, 1024, 0, stream>>>(cnt, tmpS, bsum);
  k_scanB <<<1, 512, 0, stream>>>(bsum, boff);
  k_scanC <<<SCANB, 1024, 0, stream>>>(cnt, tmpS, boff, bstart);
  k_bplace<<<NBB, 512, 0, stream>>>(srcI, dstI, cnt, epk);
  k_bsort <<<NBUK, 256, 0, stream>>>(bstart, epk, srcS, rowptr, dinv, x, flag, xd);

  // layer 1 (2 -> 64): fused propagate + transform + relu
  k_prop1<<<(NN+255)/256, 256, 0, stream>>>(rowptr, srcS, xd, Wc, dinv, h);

  // layer 2 (64 -> 64)
  k_transform64<<<(NN+63)/64, 256, 0, stream>>>(h, Wc+W2F, dinv, s);
  k_aggregate  <<<NN/4, 256, 0, stream>>>(rowptr, srcS, s, dinv, Wc+B2F, h);

  // layer 3 (64 -> 64)
  k_transform64<<<(NN+63)/64, 256, 0, stream>>>(h, Wc+W3F, dinv, s);
  k_aggregate  <<<NN/4, 256, 0, stream>>>(rowptr, srcS, s, dinv, Wc+B3F, h);

  // fc1 + fc2 (register-tiled GEMMs, split — fused version regressed 74 µs:
  // 1.36e7 LDS bank conflicts + 20% occupancy + per-16-row barrier serialization)
  k_fc1<<<(NN+63)/64, 256, 0, stream>>>(h, Wc, f);
  k_fc2<<<(NN+63)/64, 256, 0, stream>>>(f, Wc, flag, d_out);
}

// Round 14
// 325.814 us; speedup vs baseline: 1.1451x; 1.0100x over previous
//
#include <hip/hip_runtime.h>
#include <hip/hip_bf16.h>

#define NN 100000
#define NE 1600000
#define NBUK 1563          // ceil(NN/64) 64-node dst buckets
#define NBB  196           // histogram/place blocks (8192 edges each)
#define BATCH 8192
#define CNTSZ (NBUK*NBB)   // 306348
#define SCANB 300          // ceil(CNTSZ/1024)

using bf16 = __hip_bfloat16;
typedef unsigned short us8_t __attribute__((ext_vector_type(8)));
static __device__ __forceinline__ float b2f(bf16 v){ return __bfloat162float(v); }
static __device__ __forceinline__ bf16 f2b(float v){ return __float2bfloat16(v); }
static __device__ __forceinline__ float us2f(unsigned u){
  unsigned x = u<<16; float f; __builtin_memcpy(&f,&x,4); return f;
}
static __device__ __forceinline__ unsigned short f2us(float v){
  bf16 b = f2b(v); unsigned short u; __builtin_memcpy(&u,&b,2); return u;
}

// canonical f32 weight-pool offsets (floats)
#define W1F   0
#define B1F   128
#define W2F   192
#define B2F   4288
#define W3F   4352
#define B3F   8448
#define FW1F  8512
#define FB1F  16704
#define FW2F  16832
#define FB2F  20928
#define WTOT  20960

// ---- dtype sniff (f32 vs bf16 storage), multi-block ----
__global__ void k_flag0(int* flag){ if(threadIdx.x==0) *flag = 0; }
__global__ void k_sniffB(const unsigned short* __restrict__ xr, int* flag){
  __shared__ int found;
  if(threadIdx.x==0) found = 0;
  __syncthreads();
  int loc = 0;
  for(int si = blockIdx.x*256 + threadIdx.x; si < 100000; si += 98*256){
    unsigned e = (xr[si*2]>>7)&0xFF;
    if(e==0xFFu || e==0u) loc = 1;
  }
  if(loc) found = 1;
  __syncthreads();
  if(threadIdx.x==0 && found) atomicOr(flag, 1);   // 1 = f32 storage
}

// convert all weights/biases into canonical f32 pool — one element/thread
__global__ void k_convert_w(const void* p0,const void* p1,const void* p2,const void* p3,
                            const void* p4,const void* p5,const void* p6,const void* p7,
                            const void* p8,const void* p9,
                            const int* __restrict__ flag, float* __restrict__ Wc){
  int t = blockIdx.x*256 + threadIdx.x;
  if(t >= WTOT) return;
  const void* ps[10] = {p0,p1,p2,p3,p4,p5,p6,p7,p8,p9};
  const int off[11] = {W1F,B1F,W2F,B2F,W3F,B3F,FW1F,FB1F,FW2F,FB2F,WTOT};
  int seg = 0;
  while(off[seg+1] <= t) seg++;
  int j = t - off[seg];
  Wc[t] = (*flag) ? ((const float*)ps[seg])[j] : b2f(((const bf16*)ps[seg])[j]);
}

// ---------------- bucket-CSR build ----------------
// int4 edge loads: BATCH (8192) and NE (1.6M) are 4-divisible, so every
// block's [e0,e1) range is int4-aligned.
__global__ void k_bhist(const int* __restrict__ dst, int* __restrict__ cnt){
  __shared__ int hist[NBUK];
  for(int j=threadIdx.x; j<NBUK; j+=512) hist[j] = 0;
  __syncthreads();
  int e0 = blockIdx.x*BATCH;
  int e1 = min(NE, e0+BATCH);
  int q0 = e0>>2, q1 = e1>>2;
  const int4* d4 = (const int4*)dst;
  for(int q=q0+threadIdx.x; q<q1; q+=512){
    int4 d = d4[q];
    atomicAdd(&hist[d.x>>6], 1);
    atomicAdd(&hist[d.y>>6], 1);
    atomicAdd(&hist[d.z>>6], 1);
    atomicAdd(&hist[d.w>>6], 1);
  }
  __syncthreads();
  for(int j=threadIdx.x; j<NBUK; j+=512) cnt[j*NBB + blockIdx.x] = hist[j];
}
__global__ void k_scanA(const int* __restrict__ cnt, int* __restrict__ tmp,
                        int* __restrict__ bsum){
  __shared__ int sh[1024];
  int gi = blockIdx.x*1024 + threadIdx.x;
  int v = (gi < CNTSZ) ? cnt[gi] : 0;
  sh[threadIdx.x] = v; __syncthreads();
  for(int off=1; off<1024; off<<=1){
    int t = (threadIdx.x>=off) ? sh[threadIdx.x-off] : 0;
    __syncthreads();
    sh[threadIdx.x] += t;
    __syncthreads();
  }
  if(gi < CNTSZ) tmp[gi] = sh[threadIdx.x];
  if(threadIdx.x == 1023) bsum[blockIdx.x] = sh[1023];
}
__global__ void k_scanB(const int* __restrict__ bsum, int* __restrict__ boff){
  __shared__ int sh[512];
  int v = (threadIdx.x < SCANB) ? bsum[threadIdx.x] : 0;
  sh[threadIdx.x] = v; __syncthreads();
  for(int off=1; off<512; off<<=1){
    int t = (threadIdx.x>=off) ? sh[threadIdx.x-off] : 0;
    __syncthreads();
    sh[threadIdx.x] += t;
    __syncthreads();
  }
  boff[threadIdx.x] = sh[threadIdx.x] - v;   // exclusive
}
__global__ void k_scanC(int* __restrict__ cnt, const int* __restrict__ tmp,
                        const int* __restrict__ boff, int* __restrict__ bucketStart){
  int gi = blockIdx.x*1024 + threadIdx.x;
  if(gi < CNTSZ){
    int orig = cnt[gi];
    int excl = tmp[gi] - orig + boff[gi>>10];
    cnt[gi] = excl;
    if(gi % NBB == 0) bucketStart[gi/NBB] = excl;
  }
  if(gi == 0) bucketStart[NBUK] = NE;
}
__global__ void k_bplace(const int* __restrict__ src, const int* __restrict__ dst,
                         const int* __restrict__ cnt, int* __restrict__ epk){
  __shared__ int cur[NBUK];
  for(int j=threadIdx.x; j<NBUK; j+=512) cur[j] = cnt[j*NBB + blockIdx.x];
  __syncthreads();
  int e0 = blockIdx.x*BATCH, e1 = min(NE, e0+BATCH);
  int q0 = e0>>2, q1 = e1>>2;
  const int4* d4 = (const int4*)dst;
  const int4* s4 = (const int4*)src;
  for(int q=q0+threadIdx.x; q<q1; q+=512){
    int4 d = d4[q];
    int4 s = s4[q];
    int p0 = atomicAdd(&cur[d.x>>6], 1);
    int p1 = atomicAdd(&cur[d.y>>6], 1);
    int p2 = atomicAdd(&cur[d.z>>6], 1);
    int p3 = atomicAdd(&cur[d.w>>6], 1);
    epk[p0] = (s.x<<6) | (d.x&63);
    epk[p1] = (s.y<<6) | (d.y&63);
    epk[p2] = (s.z<<6) | (d.z&63);
    epk[p3] = (s.w<<6) | (d.w&63);
  }
}
// in-bucket counting sort -> exact CSR (rowptr, srcS) + dinv + xd (fused)
__global__ void k_bsort(const int* __restrict__ bucketStart, const int* __restrict__ epk,
                        int* __restrict__ srcS, int* __restrict__ rowptr,
                        float* __restrict__ dinv, const void* __restrict__ xv,
                        const int* __restrict__ flag, float2* __restrict__ xd){
  __shared__ int hist[64], excl[64], cur[64];
  int tid = threadIdx.x;
  if(tid < 64) hist[tid] = 0;
  __syncthreads();
  int b = blockIdx.x, beg = bucketStart[b], end = bucketStart[b+1];
  for(int p=beg+tid; p<end; p+=512) atomicAdd(&hist[epk[p]&63], 1);
  __syncthreads();
  if(tid == 0){
    int run = 0;
    for(int j=0;j<64;j++){ excl[j] = run; run += hist[j]; }
  }
  __syncthreads();
  if(tid < 64){
    int g = b*64 + tid;
    if(g < NN){
      rowptr[g] = beg + excl[tid];
      float d = rsqrtf((float)(hist[tid] + 1));   // +1 self-loop
      dinv[g]  = d;
      float x0, x1;
      if(*flag){ float2 p = ((const float2*)xv)[g]; x0=p.x; x1=p.y; }
      else     { const bf16* xp=(const bf16*)xv; x0=b2f(xp[2*g]); x1=b2f(xp[2*g+1]); }
      xd[g] = make_float2(x0*d, x1*d);
    }
    cur[tid] = excl[tid];
  }
  if(b == 0 && tid == 0) rowptr[NN] = NE;
  __syncthreads();
  for(int p=beg+tid; p<end; p+=512){
    int pk = epk[p];
    int pos = atomicAdd(&cur[pk&63], 1);
    srcS[beg+pos] = pk>>6;
  }
}

// ---------------- layer 1 fused: propagate x (8B gathers) + 2->64 transform + relu ----------------
__global__ void k_prop1(const int* __restrict__ rowptr, const int* __restrict__ srcS,
                        const float2* __restrict__ xd, const float* __restrict__ Wc,
                        const float* __restrict__ dinv, bf16* __restrict__ h){
  __shared__ float W1s[128];
  __shared__ float bs[64];
  if(threadIdx.x < 128) W1s[threadIdx.x] = Wc[W1F + threadIdx.x];
  if(threadIdx.x < 64)  bs[threadIdx.x]  = Wc[B1F + threadIdx.x];
  __syncthreads();
  int i = blockIdx.x*256 + threadIdx.x;
  if(i >= NN) return;
  int beg = rowptr[i], end = rowptr[i+1];
  float2 self = xd[i];
  float ax[8] = {self.x,0,0,0,0,0,0,0};
  float ay[8] = {self.y,0,0,0,0,0,0,0};
  int p = beg;
  for(; p+8 <= end; p += 8){
    int sI[8];
    #pragma unroll
    for(int j=0;j<8;j++) sI[j] = srcS[p+j];
    float2 v[8];
    #pragma unroll
    for(int j=0;j<8;j++) v[j] = xd[sI[j]];
    #pragma unroll
    for(int j=0;j<8;j++){ ax[j] += v[j].x; ay[j] += v[j].y; }
  }
  for(; p<end; p++){ float2 v=xd[srcS[p]]; ax[0]+=v.x; ay[0]+=v.y; }
  float y0 = ((ax[0]+ax[1])+(ax[2]+ax[3]))+((ax[4]+ax[5])+(ax[6]+ax[7]));
  float y1 = ((ay[0]+ay[1])+(ay[2]+ay[3]))+((ay[4]+ay[5])+(ay[6]+ay[7]));
  float d = dinv[i];
  unsigned short* hp = (unsigned short*)h + (size_t)i*64;
  #pragma unroll
  for(int g=0; g<8; g++){
    us8_t o;
    #pragma unroll
    for(int j=0;j<8;j++){
      int c = g*8+j;
      o[j] = f2us(fmaxf(d*(y0*W1s[c] + y1*W1s[64+c]) + bs[c], 0.0f));
    }
    *(us8_t*)(hp + g*8) = o;
  }
}

// ---------------- 64->64 transform (LDS-tiled GEMM, 4x4 tile/thread) ----------------
__global__ void __launch_bounds__(256) k_transform64(
    const bf16* __restrict__ h, const float* __restrict__ W,
    const float* __restrict__ dinv, bf16* __restrict__ s){
  __shared__ float Ws[64*64];
  __shared__ float hs[64][68];
  __shared__ float dl[64];
  int tid = threadIdx.x;
  for(int j=tid; j<4096; j+=256) Ws[j] = W[j];
  int row0 = blockIdx.x*64;
  if(tid < 64){ int r = row0+tid; dl[tid] = (r<NN)? dinv[r] : 0.0f; }
  for(int ch = tid; ch < 512; ch += 256){
    int r = ch>>3, c8 = (ch&7)*8;
    int gr = row0 + r;
    float f[8];
    if(gr < NN){
      us8_t v = *(const us8_t*)((const unsigned short*)h + (size_t)gr*64 + c8);
      #pragma unroll
      for(int j=0;j<8;j++) f[j] = us2f(v[j]);
    } else {
      #pragma unroll
      for(int j=0;j<8;j++) f[j] = 0.0f;
    }
    *(float4*)&hs[r][c8]   = make_float4(f[0],f[1],f[2],f[3]);
    *(float4*)&hs[r][c8+4] = make_float4(f[4],f[5],f[6],f[7]);
  }
  __syncthreads();
  int ty = tid>>4, tx = tid&15;
  float acc[4][4] = {{0}};
  #pragma unroll 8
  for(int k=0;k<64;k++){
    float4 b4 = *(const float4*)&Ws[k*64 + tx*4];
    float a0 = hs[ty*4+0][k];
    float a1 = hs[ty*4+1][k];
    float a2 = hs[ty*4+2][k];
    float a3 = hs[ty*4+3][k];
    acc[0][0] = fmaf(a0,b4.x,acc[0][0]); acc[0][1] = fmaf(a0,b4.y,acc[0][1]);
    acc[0][2] = fmaf(a0,b4.z,acc[0][2]); acc[0][3] = fmaf(a0,b4.w,acc[0][3]);
    acc[1][0] = fmaf(a1,b4.x,acc[1][0]); acc[1][1] = fmaf(a1,b4.y,acc[1][1]);
    acc[1][2] = fmaf(a1,b4.z,acc[1][2]); acc[1][3] = fmaf(a1,b4.w,acc[1][3]);
    acc[2][0] = fmaf(a2,b4.x,acc[2][0]); acc[2][1] = fmaf(a2,b4.y,acc[2][1]);
    acc[2][2] = fmaf(a2,b4.z,acc[2][2]); acc[2][3] = fmaf(a2,b4.w,acc[2][3]);
    acc[3][0] = fmaf(a3,b4.x,acc[3][0]); acc[3][1] = fmaf(a3,b4.y,acc[3][1]);
    acc[3][2] = fmaf(a3,b4.z,acc[3][2]); acc[3][3] = fmaf(a3,b4.w,acc[3][3]);
  }
  #pragma unroll
  for(int rr=0; rr<4; rr++){
    int r = row0 + ty*4 + rr;
    if(r < NN){
      float dv = dl[ty*4+rr];
      unsigned lo = f2us(acc[rr][0]*dv) | ((unsigned)f2us(acc[rr][1]*dv) << 16);
      unsigned hi = f2us(acc[rr][2]*dv) | ((unsigned)f2us(acc[rr][3]*dv) << 16);
      uint2 o; o.x = lo; o.y = hi;
      *(uint2*)((unsigned short*)s + (size_t)r*64 + tx*4) = o;
    }
  }
}

// ---------------- CSR aggregate + finalize: wave per node, 8 edges per wave-load ----------------
__global__ void __launch_bounds__(256) k_aggregate(
    const int* __restrict__ rowptr, const int* __restrict__ srcS,
    const bf16* __restrict__ s, const float* __restrict__ dinv,
    const float* __restrict__ bias, bf16* __restrict__ h){
  int wave = threadIdx.x>>6, lane = threadIdx.x&63;
  int i = blockIdx.x*4 + wave;            // grid = NN/4 = 25000 blocks
  if(i >= NN) return;
  int beg = rowptr[i], end = rowptr[i+1];
  int slot = lane>>3, oct = lane&7;
  const unsigned short* sp = (const unsigned short*)s;
  float a0[8] = {0,0,0,0,0,0,0,0};
  float a1[8] = {0,0,0,0,0,0,0,0};
  int p = beg;
  for(; p+16 <= end; p += 16){            // 16 edges in flight (2 per lane)
    int e0 = srcS[p + slot];
    int e1 = srcS[p + 8 + slot];
    us8_t v0 = *(const us8_t*)(sp + (size_t)e0*64 + oct*8);
    us8_t v1 = *(const us8_t*)(sp + (size_t)e1*64 + oct*8);
    #pragma unroll
    for(int j=0;j<8;j++){ a0[j] += us2f(v0[j]); a1[j] += us2f(v1[j]); }
  }
  for(; p+8 <= end; p += 8){
    int e0 = srcS[p + slot];
    us8_t v0 = *(const us8_t*)(sp + (size_t)e0*64 + oct*8);
    #pragma unroll
    for(int j=0;j<8;j++) a0[j] += us2f(v0[j]);
  }
  int rem = end - p;                      // 0..7 tail, one edge per low slot
  if(slot < rem){
    int e0 = srcS[p + slot];
    us8_t v0 = *(const us8_t*)(sp + (size_t)e0*64 + oct*8);
    #pragma unroll
    for(int j=0;j<8;j++) a1[j] += us2f(v0[j]);
  }
  float c[8];
  #pragma unroll
  for(int j=0;j<8;j++){
    float v = a0[j] + a1[j];
    v += __shfl_xor(v, 8, 64);
    v += __shfl_xor(v, 16, 64);
    v += __shfl_xor(v, 32, 64);
    c[j] = v;
  }
  us8_t sv = *(const us8_t*)(sp + (size_t)i*64 + oct*8);
  float dv = dinv[i];
  us8_t o;
  #pragma unroll
  for(int j=0;j<8;j++){
    float v = c[j] + us2f(sv[j]);
    o[j] = f2us(fmaxf(fmaf(dv, v, bias[oct*8+j]), 0.0f));
  }
  if(slot == 0)
    *(us8_t*)((unsigned short*)h + (size_t)i*64 + oct*8) = o;
}

// ---------------- fc1: [NN x 64] @ [64 x 128] + b, relu -> f (bf16) ----------------
__global__ void __launch_bounds__(256) k_fc1(const bf16* __restrict__ h,
                                             const float* __restrict__ Wc,
                                             bf16* __restrict__ f){
  __shared__ float W1s[64*128];
  __shared__ float hs[64][68];
  __shared__ float bs[128];
  int tid = threadIdx.x;
  for(int j=tid; j<8192; j+=256) W1s[j] = Wc[FW1F+j];
  if(tid < 128) bs[tid] = Wc[FB1F+tid];
  int row0 = blockIdx.x*64;
  for(int ch = tid; ch < 512; ch += 256){
    int r = ch>>3, c8 = (ch&7)*8, gr = row0 + r;
    float fv[8];
    if(gr < NN){
      us8_t v = *(const us8_t*)((const unsigned short*)h + (size_t)gr*64 + c8);
      #pragma unroll
      for(int j=0;j<8;j++) fv[j] = us2f(v[j]);
    } else {
      #pragma unroll
      for(int j=0;j<8;j++) fv[j] = 0.0f;
    }
    *(float4*)&hs[r][c8]   = make_float4(fv[0],fv[1],fv[2],fv[3]);
    *(float4*)&hs[r][c8+4] = make_float4(fv[4],fv[5],fv[6],fv[7]);
  }
  __syncthreads();
  int ty = tid>>4, tx = tid&15;
  float acc[4][8] = {{0}};
  #pragma unroll 4
  for(int k=0;k<64;k++){
    float4 b0 = *(const float4*)&W1s[k*128 + tx*8];
    float4 b1 = *(const float4*)&W1s[k*128 + tx*8 + 4];
    float a0 = hs[ty*4+0][k], a1 = hs[ty*4+1][k];
    float a2 = hs[ty*4+2][k], a3 = hs[ty*4+3][k];
    acc[0][0]=fmaf(a0,b0.x,acc[0][0]); acc[0][1]=fmaf(a0,b0.y,acc[0][1]);
    acc[0][2]=fmaf(a0,b0.z,acc[0][2]); acc[0][3]=fmaf(a0,b0.w,acc[0][3]);
    acc[0][4]=fmaf(a0,b1.x,acc[0][4]); acc[0][5]=fmaf(a0,b1.y,acc[0][5]);
    acc[0][6]=fmaf(a0,b1.z,acc[0][6]); acc[0][7]=fmaf(a0,b1.w,acc[0][7]);
    acc[1][0]=fmaf(a1,b0.x,acc[1][0]); acc[1][1]=fmaf(a1,b0.y,acc[1][1]);
    acc[1][2]=fmaf(a1,b0.z,acc[1][2]); acc[1][3]=fmaf(a1,b0.w,acc[1][3]);
    acc[1][4]=fmaf(a1,b1.x,acc[1][4]); acc[1][5]=fmaf(a1,b1.y,acc[1][5]);
    acc[1][6]=fmaf(a1,b1.z,acc[1][6]); acc[1][7]=fmaf(a1,b1.w,acc[1][7]);
    acc[2][0]=fmaf(a2,b0.x,acc[2][0]); acc[2][1]=fmaf(a2,b0.y,acc[2][1]);
    acc[2][2]=fmaf(a2,b0.z,acc[2][2]); acc[2][3]=fmaf(a2,b0.w,acc[2][3]);
    acc[2][4]=fmaf(a2,b1.x,acc[2][4]); acc[2][5]=fmaf(a2,b1.y,acc[2][5]);
    acc[2][6]=fmaf(a2,b1.z,acc[2][6]); acc[2][7]=fmaf(a2,b1.w,acc[2][7]);
    acc[3][0]=fmaf(a3,b0.x,acc[3][0]); acc[3][1]=fmaf(a3,b0.y,acc[3][1]);
    acc[3][2]=fmaf(a3,b0.z,acc[3][2]); acc[3][3]=fmaf(a3,b0.w,acc[3][3]);
    acc[3][4]=fmaf(a3,b1.x,acc[3][4]); acc[3][5]=fmaf(a3,b1.y,acc[3][5]);
    acc[3][6]=fmaf(a3,b1.z,acc[3][6]); acc[3][7]=fmaf(a3,b1.w,acc[3][7]);
  }
  #pragma unroll
  for(int r=0;r<4;r++){
    int gr = row0 + ty*4 + r;
    if(gr < NN){
      us8_t o;
      #pragma unroll
      for(int j=0;j<8;j++) o[j] = f2us(fmaxf(acc[r][j] + bs[tx*8+j], 0.0f));
      *(us8_t*)((unsigned short*)f + (size_t)gr*128 + tx*8) = o;
    }
  }
}

// ---------------- fc2: [NN x 128] @ [128 x 32] + b -> out ----------------
__global__ void __launch_bounds__(256) k_fc2(const bf16* __restrict__ f,
                                             const float* __restrict__ Wc,
                                             const int* __restrict__ flag,
                                             void* __restrict__ outv){
  __shared__ float W2s[128*32];
  __shared__ float fs[64][132];
  __shared__ float bs[32];
  int tid = threadIdx.x;
  for(int j=tid; j<4096; j+=256) W2s[j] = Wc[FW2F+j];
  if(tid < 32) bs[tid] = Wc[FB2F+tid];
  int row0 = blockIdx.x*64;
  for(int ch = tid; ch < 1024; ch += 256){
    int r = ch>>4, c8 = (ch&15)*8, gr = row0 + r;
    float fv[8];
    if(gr < NN){
      us8_t v = *(const us8_t*)((const unsigned short*)f + (size_t)gr*128 + c8);
      #pragma unroll
      for(int j=0;j<8;j++) fv[j] = us2f(v[j]);
    } else {
      #pragma unroll
      for(int j=0;j<8;j++) fv[j] = 0.0f;
    }
    *(float4*)&fs[r][c8]   = make_float4(fv[0],fv[1],fv[2],fv[3]);
    *(float4*)&fs[r][c8+4] = make_float4(fv[4],fv[5],fv[6],fv[7]);
  }
  __syncthreads();
  int ty = tid>>3, tx = tid&7;
  float acc[2][4] = {{0}};
  #pragma unroll 8
  for(int k=0;k<128;k++){
    float4 b4 = *(const float4*)&W2s[k*32 + tx*4];
    float a0 = fs[ty*2+0][k], a1 = fs[ty*2+1][k];
    acc[0][0]=fmaf(a0,b4.x,acc[0][0]); acc[0][1]=fmaf(a0,b4.y,acc[0][1]);
    acc[0][2]=fmaf(a0,b4.z,acc[0][2]); acc[0][3]=fmaf(a0,b4.w,acc[0][3]);
    acc[1][0]=fmaf(a1,b4.x,acc[1][0]); acc[1][1]=fmaf(a1,b4.y,acc[1][1]);
    acc[1][2]=fmaf(a1,b4.z,acc[1][2]); acc[1][3]=fmaf(a1,b4.w,acc[1][3]);
  }
  int fl = *flag;
  #pragma unroll
  for(int r=0;r<2;r++){
    int gr = row0 + ty*2 + r;
    if(gr < NN){
      float o0 = acc[r][0]+bs[tx*4+0], o1 = acc[r][1]+bs[tx*4+1];
      float o2 = acc[r][2]+bs[tx*4+2], o3 = acc[r][3]+bs[tx*4+3];
      if(fl){
        *(float4*)((float*)outv + (size_t)gr*32 + tx*4) = make_float4(o0,o1,o2,o3);
      } else {
        unsigned lo = f2us(o0) | ((unsigned)f2us(o1)<<16);
        unsigned hi = f2us(o2) | ((unsigned)f2us(o3)<<16);
        uint2 o; o.x = lo; o.y = hi;
        *(uint2*)((unsigned short*)outv + (size_t)gr*32 + tx*4) = o;
      }
    }
  }
}

extern "C" void kernel_launch(void* const* d_in, const int* in_sizes, int n_in,
                              void* d_out, int out_size, void* d_ws, size_t ws_size,
                              hipStream_t stream){
  const void* x   = d_in[0];
  const int*  ei  = (const int*)d_in[1];
  const int* srcI = ei;        // edge_index[0]
  const int* dstI = ei + NE;   // edge_index[1]

  // workspace layout (bytes); total ~68 MB
  char*   base   = (char*)d_ws;
  int*    flag   = (int*)   (base + 0);          // 256
  float*  Wc     = (float*) (base + 256);        // 83840 -> 84096
  int*    bstart = (int*)   (base + 84224);      // 6256
  int*    cnt    = (int*)   (base + 90624);      // 1225392
  int*    tmpS   = (int*)   (base + 1316096);    // 1225392
  int*    bsum   = (int*)   (base + 2541568);    // 2048
  int*    boff   = (int*)   (base + 2543616);    // 2048
  float*  dinv   = (float*) (base + 2545664);    // 400000
  int*    rowptr = (int*)   (base + 2945664);    // 400004
  int*    epk    = (int*)   (base + 3345792);    // 6400000
  int*    srcS   = (int*)   (base + 9745792);    // 6400000
  float2* xd     = (float2*)(base + 16145792);   // 800000
  bf16*   s      = (bf16*)  (base + 16945792);   // 12800000
  bf16*   h      = (bf16*)  (base + 29745792);   // 12800000
  bf16*   f      = (bf16*)  (base + 42545792);   // 25600000 -> ends 68145792

  // dtype sniff + weight conversion
  k_flag0    <<<1, 64, 0, stream>>>(flag);
  k_sniffB   <<<98, 256, 0, stream>>>((const unsigned short*)x, flag);
  k_convert_w<<<(WTOT+255)/256, 256, 0, stream>>>(
      d_in[2], d_in[3], d_in[4], d_in[5], d_in[6],
      d_in[7], d_in[8], d_in[9], d_in[10], d_in[11], flag, Wc);

  // bucket-grouped build: hist -> parallel scan -> place -> in-bucket sort (+xd)
  k_bhist <<<NBB, 512, 0, stream>>>(dstI, cnt);
  k_scanA <<<SCANB, 1024, 0, stream>>>(cnt, tmpS, bsum);
  k_scanB <<<1, 512, 0, stream>>>(bsum, boff);
  k_scanC <<<SCANB, 1024, 0, stream>>>(cnt, tmpS, boff, bstart);
  k_bplace<<<NBB, 512, 0, stream>>>(srcI, dstI, cnt, epk);
  k_bsort <<<NBUK, 512, 0, stream>>>(bstart, epk, srcS, rowptr, dinv, x, flag, xd);

  // layer 1 (2 -> 64): fused propagate + transform + relu
  k_prop1<<<(NN+255)/256, 256, 0, stream>>>(rowptr, srcS, xd, Wc, dinv, h);

  // layer 2 (64 -> 64)
  k_transform64<<<(NN+63)/64, 256, 0, stream>>>(h, Wc+W2F, dinv, s);
  k_aggregate  <<<NN/4, 256, 0, stream>>>(rowptr, srcS, s, dinv, Wc+B2F, h);

  // layer 3 (64 -> 64)
  k_transform64<<<(NN+63)/64, 256, 0, stream>>>(h, Wc+W3F, dinv, s);
  k_aggregate  <<<NN/4, 256, 0, stream>>>(rowptr, srcS, s, dinv, Wc+B3F, h);

  // fc1 + fc2 (register-tiled GEMMs, split — fused version regressed 74 µs)
  k_fc1<<<(NN+63)/64, 256, 0, stream>>>(h, Wc, f);
  k_fc2<<<(NN+63)/64, 256, 0, stream>>>(f, Wc, flag, d_out);
}